// Round 1
// baseline (243.540 us; speedup 1.0000x reference)
//
#include <hip/hip_runtime.h>

#define NB 2048
#define DD 128
#define HH 256
#define KF 32768   /* HH*DD, kappa = h*128+d == original Wh row index */
#define LN_EPS 1e-5f
#define KSPLIT 16
#define KSL (KF / KSPLIT)   /* 2048 = 16 h-values x 128 d */

typedef __attribute__((ext_vector_type(8))) short short8;
typedef __attribute__((ext_vector_type(4))) float float4_t;
typedef __attribute__((ext_vector_type(4))) float f4;

__device__ __forceinline__ unsigned short f2bf(float f) {
    unsigned int u = __builtin_bit_cast(unsigned int, f);
    u += 0x7fffu + ((u >> 16) & 1u);   // RNE
    return (unsigned short)(u >> 16);
}

__device__ __forceinline__ unsigned int pkbf(float lo, float hi) {
    unsigned int r;
    asm("v_cvt_pk_bf16_f32 %0, %1, %2" : "=v"(r) : "v"(lo), "v"(hi));
    return r;
}

__device__ __forceinline__ void gl2lds16(const void* g, void* l) {
    __builtin_amdgcn_global_load_lds(
        (const __attribute__((address_space(1))) unsigned int*)g,
        (__attribute__((address_space(3))) unsigned int*)l, 16, 0, 0);
}

// ---------------------------------------------------------------------------
// Kernel 1: stats + Win/bin transpose + bias2 zeroing.
//  blocks 0..511  : per (n,h) LN stats of x = relu(a*Win+bin):
//                   stats[n][h] = (rs, mu*rs)        [4 MB instead of 128 MB Z]
//  blocks 512..575: 32x32 tile transpose Win->WinT[h][d], bin->binT[h][d]
//  block  576     : zero bias2[256]
// ---------------------------------------------------------------------------
__global__ void stats_k(const float* __restrict__ arr, const float* __restrict__ Win,
                        const float* __restrict__ bin, float2* __restrict__ stats,
                        float* __restrict__ WinT, float* __restrict__ binT,
                        float* __restrict__ bias2) {
    __shared__ float a_s[4][128];
    __shared__ float tile[32][33];
    int bid = blockIdx.x;
    int t = threadIdx.x;

    if (bid >= 512) {
        if (bid == 576) { bias2[t & 255] = 0.f; return; }
        int tid = bid - 512;          // 0..63
        int mat = tid >> 5;           // 0: Win, 1: bin
        int dt = (tid >> 3) & 3;      // d-tile 0..3
        int ht = tid & 7;             // h-tile 0..7
        const float* src = mat ? bin : Win;
        float* dst = mat ? binT : WinT;
        int c = t & 31, r = t >> 5;   // 32 x 8
#pragma unroll
        for (int rr = r; rr < 32; rr += 8)
            tile[rr][c] = src[(dt * 32 + rr) * 256 + ht * 32 + c];
        __syncthreads();
#pragma unroll
        for (int rr = r; rr < 32; rr += 8)
            dst[(ht * 32 + rr) * 128 + dt * 32 + c] = tile[c][rr];
        return;
    }

    int n0 = bid * 4;
    for (int i = t; i < 512; i += 256) a_s[i >> 7][i & 127] = arr[n0 * 128 + i];
    __syncthreads();
    int h = t;
    float sum[4] = {0.f, 0.f, 0.f, 0.f}, ssq[4] = {0.f, 0.f, 0.f, 0.f};
    for (int d = 0; d < 128; ++d) {
        float w = Win[d * 256 + h];
        float bb = bin[d * 256 + h];
#pragma unroll
        for (int q = 0; q < 4; ++q) {
            float x = fmaxf(fmaf(a_s[q][d], w, bb), 0.f);
            sum[q] += x;
            ssq[q] = fmaf(x, x, ssq[q]);
        }
    }
#pragma unroll
    for (int q = 0; q < 4; ++q) {
        float mu = sum[q] * (1.f / 128.f);
        float var = fmaxf(ssq[q] * (1.f / 128.f) - mu * mu, 0.f);
        float rs = rsqrtf(var + LN_EPS);
        stats[(long)(n0 + q) * HH + h] = make_float2(rs, mu * rs);
    }
}

// ---------------------------------------------------------------------------
// Kernel 2: WhbT[j][k] = bf16(g[d]*Wh[k][j]), k = h*128+d (identity -> plain
// transpose), plus bias2[j] += sum_k beta[d(k)]*Wh[k][j] (beta term of LN).
// ---------------------------------------------------------------------------
__global__ void prep_b(const float* __restrict__ Wh, const float* __restrict__ g,
                       const float* __restrict__ beta, unsigned short* __restrict__ WhbT,
                       float* __restrict__ bias2) {
    __shared__ unsigned short tile[64][65];
    __shared__ float red[4][64];
    int kb = blockIdx.x;          // k-tile 0..511
    int jb = blockIdx.y;          // j-tile 0..3
    int t = threadIdx.x;
    int c = t & 63, r4 = t >> 6;
    int k0 = kb * 64;
    float bsum = 0.f;
    for (int rr = r4; rr < 64; rr += 4) {
        int k = k0 + rr, d = k & 127;
        float v = Wh[(long)k * 256 + jb * 64 + c];
        tile[rr][c] = f2bf(g[d] * v);
        bsum = fmaf(beta[d], v, bsum);
    }
    __syncthreads();
    for (int rr = r4; rr < 64; rr += 4)
        WhbT[(long)(jb * 64 + rr) * KF + k0 + c] = tile[c][rr];
    red[r4][c] = bsum;
    __syncthreads();
    if (r4 == 0)
        atomicAdd(&bias2[jb * 64 + c], red[0][c] + red[1][c] + red[2][c] + red[3][c]);
}

// ---------------------------------------------------------------------------
// Kernel 3: fused GEMM. C[n,j] = sum_k z[n,k]*WhbT[j][k], A-fragments (z)
// generated IN REGISTERS from arr/WinT/binT/stats -- Z never touches HBM.
// BM=BN=128, BK=32 (one h, 32 d's per k-step), split-K=16.
// k-step order: q (d-quarter) outer so a-regs (32 VGPR) are reused 16x.
// ---------------------------------------------------------------------------
__global__ __launch_bounds__(256, 2) void gemm_f(
        const float* __restrict__ arr, const float* __restrict__ WinT,
        const float* __restrict__ binT, const float2* __restrict__ stats,
        const unsigned short* __restrict__ Bt,   // WhbT [256][KF]
        float* __restrict__ Cp) {
    __shared__ unsigned short Bs[128 * 32];   // 8 KB, B-tile only
    int bid = blockIdx.x;
    int ks = bid >> 5;          // 0..15 k-slice (16 h's)
    int mt = (bid >> 1) & 15;   // 0..15
    int nt = bid & 1;           // 0..1
    int m0 = mt * 128, n0 = nt * 128;
    long k0 = (long)ks * KSL;
    int h0 = ks * 16;
    int t = threadIdx.x;
    int lane = t & 63, wave = t >> 6;
    int wm = (wave >> 1) * 64, wn = (wave & 1) * 64;
    int fr = lane & 15;
    int fk8 = (lane >> 4) * 8;

    float4_t acc[4][4] = {};

    const unsigned short* Bab = Bt + (long)n0 * KF + k0;
    int s0 = t, s1 = t + 256;
    long boff0 = (long)(s0 >> 2) * KF + (long)(s0 & 3) * 8;
    long boff1 = (long)(s1 >> 2) * KF + (long)(s1 & 3) * 8;

    int row0 = m0 + wm + fr;

    for (int q = 0; q < 4; ++q) {
        // a[row, q*32+fk8 .. +8] for the 4 m-frags: 32 VGPR, reused for 16 h's
        f4 a0[4], a1[4];
#pragma unroll
        for (int mi = 0; mi < 4; ++mi) {
            const float* ap = arr + (long)(row0 + mi * 16) * DD + q * 32 + fk8;
            a0[mi] = *(const f4*)ap;
            a1[mi] = *(const f4*)(ap + 4);
        }
        for (int hl = 0; hl < 16; ++hl) {
            int kb = hl * 128 + q * 32;   // kappa offset inside the k-slice
            __syncthreads();              // everyone done reading Bs
            gl2lds16(Bab + kb + boff0, &Bs[s0 * 8]);
            gl2lds16(Bab + kb + boff1, &Bs[s1 * 8]);
            int h = h0 + hl;
            const float* wp = WinT + h * DD + q * 32 + fk8;
            const float* bp = binT + h * DD + q * 32 + fk8;
            f4 w0 = *(const f4*)wp, w1 = *(const f4*)(wp + 4);
            f4 v0 = *(const f4*)bp, v1 = *(const f4*)(bp + 4);
            // z-gen VALU hides the global_load_lds latency before the barrier
            short8 af[4];
#pragma unroll
            for (int mi = 0; mi < 4; ++mi) {
                float2 sv = stats[(long)(row0 + mi * 16) * HH + h];
                float rs = sv.x, nm = -sv.y;
                float z0 = fmaf(fmaxf(fmaf(a0[mi][0], w0[0], v0[0]), 0.f), rs, nm);
                float z1 = fmaf(fmaxf(fmaf(a0[mi][1], w0[1], v0[1]), 0.f), rs, nm);
                float z2 = fmaf(fmaxf(fmaf(a0[mi][2], w0[2], v0[2]), 0.f), rs, nm);
                float z3 = fmaf(fmaxf(fmaf(a0[mi][3], w0[3], v0[3]), 0.f), rs, nm);
                float z4 = fmaf(fmaxf(fmaf(a1[mi][0], w1[0], v1[0]), 0.f), rs, nm);
                float z5 = fmaf(fmaxf(fmaf(a1[mi][1], w1[1], v1[1]), 0.f), rs, nm);
                float z6 = fmaf(fmaxf(fmaf(a1[mi][2], w1[2], v1[2]), 0.f), rs, nm);
                float z7 = fmaf(fmaxf(fmaf(a1[mi][3], w1[3], v1[3]), 0.f), rs, nm);
                union { short8 s; unsigned int u[4]; } pk;
                pk.u[0] = pkbf(z0, z1);
                pk.u[1] = pkbf(z2, z3);
                pk.u[2] = pkbf(z4, z5);
                pk.u[3] = pkbf(z6, z7);
                af[mi] = pk.s;
            }
            __syncthreads();              // Bs ready
            short8 bfv[4];
#pragma unroll
            for (int i = 0; i < 4; ++i)
                bfv[i] = *(const short8*)&Bs[(wn + i * 16 + fr) * 32 + fk8];
#pragma unroll
            for (int mi = 0; mi < 4; ++mi)
#pragma unroll
                for (int ni = 0; ni < 4; ++ni)
                    acc[mi][ni] = __builtin_amdgcn_mfma_f32_16x16x32_bf16(
                        af[mi], bfv[ni], acc[mi][ni], 0, 0, 0);
        }
    }

    // epilogue: C/D layout col=lane&15, row=(lane>>4)*4+reg  [m89-verified]
    int rb = (lane >> 4) * 4;
    float* Cb = Cp + (long)ks * NB * 256;
#pragma unroll
    for (int mi = 0; mi < 4; ++mi) {
#pragma unroll
        for (int ni = 0; ni < 4; ++ni) {
            int n = n0 + wn + ni * 16 + fr;
#pragma unroll
            for (int r = 0; r < 4; ++r) {
                int m = m0 + wm + mi * 16 + rb + r;
                Cb[(long)m * 256 + n] = acc[mi][ni][r];
            }
        }
    }
}

// ---------------------------------------------------------------------------
// Kernel 4: out[n] = bo + sum_j Wo[j]*relu(bh[j] + bias2[j] + sum_s Cp[s][n][j])
// ---------------------------------------------------------------------------
__global__ void finale(const float* __restrict__ Cp, const float* __restrict__ bh,
                       const float* __restrict__ Wo, const float* __restrict__ bo,
                       const float* __restrict__ bias2, float* __restrict__ out) {
    __shared__ float red[4];
    int n = blockIdx.x, t = threadIdx.x;
    int lane = t & 63, wave = t >> 6;
    float s = bh[t] + bias2[t];
    for (int sl = 0; sl < KSPLIT; ++sl)
        s += Cp[(long)sl * NB * 256 + (long)n * 256 + t];
    float v = fmaxf(s, 0.f) * Wo[t];
#pragma unroll
    for (int o = 32; o; o >>= 1) v += __shfl_down(v, o);
    if (lane == 0) red[wave] = v;
    __syncthreads();
    if (t == 0) out[n] = red[0] + red[1] + red[2] + red[3] + bo[0];
}

extern "C" void kernel_launch(void* const* d_in, const int* in_sizes, int n_in,
                              void* d_out, int out_size, void* d_ws, size_t ws_size,
                              hipStream_t stream) {
    const float* arr  = (const float*)d_in[0];
    const float* Win  = (const float*)d_in[1];
    const float* bin  = (const float*)d_in[2];
    const float* ln_g = (const float*)d_in[7];
    const float* ln_b = (const float*)d_in[8];
    const float* Wh   = (const float*)d_in[9];
    const float* bh   = (const float*)d_in[10];
    const float* Wo   = (const float*)d_in[11];
    const float* bo   = (const float*)d_in[12];
    float* out = (float*)d_out;

    char* ws = (char*)d_ws;
    unsigned short* WhbT = (unsigned short*)ws;                    // 16,777,216 B
    float2* stats = (float2*)(ws + 16777216ull);                   //  4,194,304 B
    float* Cp     = (float*)(ws + 20971520ull);                    // 33,554,432 B
    float* WinT   = (float*)(ws + 54525952ull);                    //    131,072 B
    float* binT   = (float*)(ws + 54657024ull);                    //    131,072 B
    float* bias2  = (float*)(ws + 54788096ull);                    //      1,024 B

    hipLaunchKernelGGL(stats_k, dim3(577), dim3(256), 0, stream,
                       arr, Win, bin, stats, WinT, binT, bias2);
    hipLaunchKernelGGL(prep_b, dim3(512, 4), dim3(256), 0, stream,
                       Wh, ln_g, ln_b, WhbT, bias2);
    hipLaunchKernelGGL(gemm_f, dim3(512), dim3(256), 0, stream,
                       arr, WinT, binT, stats, WhbT, Cp);
    hipLaunchKernelGGL(finale, dim3(NB), dim3(256), 0, stream,
                       Cp, bh, Wo, bo, bias2, out);
}

// Round 2
// 205.211 us; speedup vs baseline: 1.1868x; 1.1868x over previous
//
#include <hip/hip_runtime.h>

#define NB 2048
#define DD 128
#define HH 256
#define KF 32768   /* HH*DD, kappa = h*128+d == original Wh row index */
#define LN_EPS 1e-5f
#define KSPLIT 16
#define KSL (KF / KSPLIT)   /* 2048 = 16 h-values x 128 d */

typedef __attribute__((ext_vector_type(8))) short short8;
typedef __attribute__((ext_vector_type(4))) float float4_t;
typedef __attribute__((ext_vector_type(4))) float f4;

__device__ __forceinline__ unsigned short f2bf(float f) {
    unsigned int u = __builtin_bit_cast(unsigned int, f);
    u += 0x7fffu + ((u >> 16) & 1u);   // RNE
    return (unsigned short)(u >> 16);
}

__device__ __forceinline__ unsigned int pkbf(float lo, float hi) {
    unsigned int r;
    asm("v_cvt_pk_bf16_f32 %0, %1, %2" : "=v"(r) : "v"(lo), "v"(hi));
    return r;
}

__device__ __forceinline__ void gl2lds16(const void* g, void* l) {
    __builtin_amdgcn_global_load_lds(
        (const __attribute__((address_space(1))) unsigned int*)g,
        (__attribute__((address_space(3))) unsigned int*)l, 16, 0, 0);
}

// ---------------------------------------------------------------------------
// Kernel 1: stats (n-batch 2, 1024 blocks) + Win/bin transpose + bias2 zero.
// ---------------------------------------------------------------------------
__global__ void stats_k(const float* __restrict__ arr, const float* __restrict__ Win,
                        const float* __restrict__ bin, float2* __restrict__ stats,
                        float* __restrict__ WinT, float* __restrict__ binT,
                        float* __restrict__ bias2) {
    __shared__ float a_s[2][128];
    __shared__ float tile[32][33];
    int bid = blockIdx.x;
    int t = threadIdx.x;

    if (bid >= 1024) {
        if (bid == 1088) { bias2[t] = 0.f; return; }
        int tid = bid - 1024;         // 0..63
        int mat = tid >> 5;           // 0: Win, 1: bin
        int dt = (tid >> 3) & 3;      // d-tile 0..3
        int ht = tid & 7;             // h-tile 0..7
        const float* src = mat ? bin : Win;
        float* dst = mat ? binT : WinT;
        int c = t & 31, r = t >> 5;   // 32 x 8
#pragma unroll
        for (int rr = r; rr < 32; rr += 8)
            tile[rr][c] = src[(dt * 32 + rr) * 256 + ht * 32 + c];
        __syncthreads();
#pragma unroll
        for (int rr = r; rr < 32; rr += 8)
            dst[(ht * 32 + rr) * 128 + dt * 32 + c] = tile[c][rr];
        return;
    }

    int n0 = bid * 2;
    if (t < 256) a_s[t >> 7][t & 127] = arr[n0 * 128 + t];
    __syncthreads();
    int h = t;
    float sum[2] = {0.f, 0.f}, ssq[2] = {0.f, 0.f};
    for (int d = 0; d < 128; ++d) {
        float w = Win[d * 256 + h];
        float bb = bin[d * 256 + h];
#pragma unroll
        for (int q = 0; q < 2; ++q) {
            float x = fmaxf(fmaf(a_s[q][d], w, bb), 0.f);
            sum[q] += x;
            ssq[q] = fmaf(x, x, ssq[q]);
        }
    }
#pragma unroll
    for (int q = 0; q < 2; ++q) {
        float mu = sum[q] * (1.f / 128.f);
        float var = fmaxf(ssq[q] * (1.f / 128.f) - mu * mu, 0.f);
        float rs = rsqrtf(var + LN_EPS);
        stats[(long)(n0 + q) * HH + h] = make_float2(rs, mu * rs);
    }
}

// ---------------------------------------------------------------------------
// Kernel 2: WhbT[j][k] = bf16(g[d]*Wh[k][j]), k = h*128+d (plain transpose),
// plus bias2[j] += sum_k beta[d(k)]*Wh[k][j].
// ---------------------------------------------------------------------------
__global__ void prep_b(const float* __restrict__ Wh, const float* __restrict__ g,
                       const float* __restrict__ beta, unsigned short* __restrict__ WhbT,
                       float* __restrict__ bias2) {
    __shared__ unsigned short tile[64][65];
    __shared__ float red[4][64];
    int kb = blockIdx.x;          // k-tile 0..511
    int jb = blockIdx.y;          // j-tile 0..3
    int t = threadIdx.x;
    int c = t & 63, r4 = t >> 6;
    int k0 = kb * 64;
    float bsum = 0.f;
    for (int rr = r4; rr < 64; rr += 4) {
        int k = k0 + rr, d = k & 127;
        float v = Wh[(long)k * 256 + jb * 64 + c];
        tile[rr][c] = f2bf(g[d] * v);
        bsum = fmaf(beta[d], v, bsum);
    }
    __syncthreads();
    for (int rr = r4; rr < 64; rr += 4)
        WhbT[(long)(jb * 64 + rr) * KF + k0 + c] = tile[c][rr];
    red[r4][c] = bsum;
    __syncthreads();
    if (r4 == 0)
        atomicAdd(&bias2[jb * 64 + c], red[0][c] + red[1][c] + red[2][c] + red[3][c]);
}

// ---------------------------------------------------------------------------
// Kernel 3: fused GEMM, 512 threads (8 waves, 4m x 2n), BM=BN=128, BK=32,
// KSPLIT=16.  One __syncthreads per k-step; B-tile for step i+1 staged at the
// top of step i (ping-pong Bs) so the barrier's vmcnt drain has a full body
// of slack.  Bs global source pre-swizzled (2-bit XOR) to cut read bank
// conflicts 8-way -> <=4-way; stats in padded LDS.
// ---------------------------------------------------------------------------
__global__ __launch_bounds__(512, 4) void gemm_f(
        const float* __restrict__ arr, const float* __restrict__ WinT,
        const float* __restrict__ binT, const float2* __restrict__ stats,
        const unsigned short* __restrict__ Bt,   // WhbT [256][KF]
        float* __restrict__ Cp) {
    __shared__ unsigned short Bs[2][128 * 32];   // 2 x 8KB ping-pong
    __shared__ float2 Ss[128 * 18];              // stats slice, +2 pad per row
    int bid = blockIdx.x;
    int ks = bid >> 5;          // 0..15 k-slice (16 h's)
    int mt = (bid >> 1) & 15;
    int nt = bid & 1;
    int m0 = mt * 128, n0 = nt * 128;
    long k0 = (long)ks * KSL;
    int h0 = ks * 16;
    int t = threadIdx.x;
    int lane = t & 63, wave = t >> 6;
    int wm = (wave >> 1) * 32;       // 4 m-groups of 32 rows
    int wn = (wave & 1) * 64;        // 2 n-groups of 64 cols
    int fr = lane & 15;
    int kch = lane >> 4;             // 0..3  (16B k-chunk)
    int fk8 = kch * 8;

    float4_t acc[2][4] = {};

    const unsigned short* Bab = Bt + (long)n0 * KF + k0;
    // staging slot: thread t -> LDS 16B slot t; holds global chunk (j, kc^(j&3))
    int j_s = t >> 2, kc_s = t & 3;
    long boff = (long)j_s * KF + (long)(((kc_s ^ (j_s & 3))) << 3);

    // prologue: stats slice -> LDS, B tile 0 -> LDS
    {
        int sr = t >> 2, sc = (t & 3) * 4;
        const float2* sp = stats + (long)(m0 + sr) * HH + h0 + sc;
        f4 v0 = *(const f4*)sp;
        f4 v1 = *(const f4*)(sp + 2);
        *(f4*)&Ss[sr * 18 + sc] = v0;
        *(f4*)&Ss[sr * 18 + sc + 2] = v1;
        gl2lds16(Bab + boff, &Bs[0][t * 8]);
    }
    int row0 = m0 + wm + fr;         // global row of m-frag 0; frag 1 = +16
    f4 aa[2][2];                      // a regs: [mi][lo/hi 4]
    __syncthreads();

    for (int it = 0; it < 64; ++it) {
        int q = it >> 4, hl = it & 15, cur = it & 1;
        // stage next B tile first: maximum slack before the end barrier
        if (it < 63) {
            int itn = it + 1;
            int kap = (itn & 15) * 128 + (itn >> 4) * 32;
            gl2lds16(Bab + kap + boff, &Bs[cur ^ 1][t * 8]);
        }
        if (hl == 0) {
#pragma unroll
            for (int mi = 0; mi < 2; ++mi) {
                const float* ap = arr + (long)(row0 + mi * 16) * DD + q * 32 + fk8;
                aa[mi][0] = *(const f4*)ap;
                aa[mi][1] = *(const f4*)(ap + 4);
            }
        }
        // B fragments (swizzled read matching the pre-swizzled source)
        short8 bfv[4];
#pragma unroll
        for (int ni = 0; ni < 4; ++ni) {
            int j = wn + ni * 16 + fr;
            bfv[ni] = *(const short8*)&Bs[cur][j * 32 + ((kch ^ (j & 3)) << 3)];
        }
        // z-gen in registers -> A fragments
        int h = h0 + hl;
        const float* wp = WinT + h * DD + q * 32 + fk8;
        const float* bp = binT + h * DD + q * 32 + fk8;
        f4 w0 = *(const f4*)wp, w1 = *(const f4*)(wp + 4);
        f4 v0 = *(const f4*)bp, v1 = *(const f4*)(bp + 4);
        short8 af[2];
#pragma unroll
        for (int mi = 0; mi < 2; ++mi) {
            float2 sv = Ss[(wm + mi * 16 + fr) * 18 + hl];
            float rs = sv.x, nm = -sv.y;
            float z0 = fmaf(fmaxf(fmaf(aa[mi][0][0], w0[0], v0[0]), 0.f), rs, nm);
            float z1 = fmaf(fmaxf(fmaf(aa[mi][0][1], w0[1], v0[1]), 0.f), rs, nm);
            float z2 = fmaf(fmaxf(fmaf(aa[mi][0][2], w0[2], v0[2]), 0.f), rs, nm);
            float z3 = fmaf(fmaxf(fmaf(aa[mi][0][3], w0[3], v0[3]), 0.f), rs, nm);
            float z4 = fmaf(fmaxf(fmaf(aa[mi][1][0], w1[0], v1[0]), 0.f), rs, nm);
            float z5 = fmaf(fmaxf(fmaf(aa[mi][1][1], w1[1], v1[1]), 0.f), rs, nm);
            float z6 = fmaf(fmaxf(fmaf(aa[mi][1][2], w1[2], v1[2]), 0.f), rs, nm);
            float z7 = fmaf(fmaxf(fmaf(aa[mi][1][3], w1[3], v1[3]), 0.f), rs, nm);
            union { short8 s; unsigned int u[4]; } pk;
            pk.u[0] = pkbf(z0, z1);
            pk.u[1] = pkbf(z2, z3);
            pk.u[2] = pkbf(z4, z5);
            pk.u[3] = pkbf(z6, z7);
            af[mi] = pk.s;
        }
#pragma unroll
        for (int mi = 0; mi < 2; ++mi)
#pragma unroll
            for (int ni = 0; ni < 4; ++ni)
                acc[mi][ni] = __builtin_amdgcn_mfma_f32_16x16x32_bf16(
                    af[mi], bfv[ni], acc[mi][ni], 0, 0, 0);
        if (it < 63) __syncthreads();
    }

    // epilogue: C/D layout col=lane&15, row=(lane>>4)*4+reg  [m89-verified]
    int rb = (lane >> 4) * 4;
    float* Cb = Cp + (long)ks * NB * 256;
#pragma unroll
    for (int mi = 0; mi < 2; ++mi) {
#pragma unroll
        for (int ni = 0; ni < 4; ++ni) {
            int n = n0 + wn + ni * 16 + fr;
#pragma unroll
            for (int r = 0; r < 4; ++r) {
                int m = m0 + wm + mi * 16 + rb + r;
                Cb[(long)m * 256 + n] = acc[mi][ni][r];
            }
        }
    }
}

// ---------------------------------------------------------------------------
// Kernel 4: out[n] = bo + sum_j Wo[j]*relu(bh[j] + bias2[j] + sum_s Cp[s][n][j])
// ---------------------------------------------------------------------------
__global__ void finale(const float* __restrict__ Cp, const float* __restrict__ bh,
                       const float* __restrict__ Wo, const float* __restrict__ bo,
                       const float* __restrict__ bias2, float* __restrict__ out) {
    __shared__ float red[4];
    int n = blockIdx.x, t = threadIdx.x;
    int lane = t & 63, wave = t >> 6;
    float s = bh[t] + bias2[t];
    for (int sl = 0; sl < KSPLIT; ++sl)
        s += Cp[(long)sl * NB * 256 + (long)n * 256 + t];
    float v = fmaxf(s, 0.f) * Wo[t];
#pragma unroll
    for (int o = 32; o; o >>= 1) v += __shfl_down(v, o);
    if (lane == 0) red[wave] = v;
    __syncthreads();
    if (t == 0) out[n] = red[0] + red[1] + red[2] + red[3] + bo[0];
}

extern "C" void kernel_launch(void* const* d_in, const int* in_sizes, int n_in,
                              void* d_out, int out_size, void* d_ws, size_t ws_size,
                              hipStream_t stream) {
    const float* arr  = (const float*)d_in[0];
    const float* Win  = (const float*)d_in[1];
    const float* bin  = (const float*)d_in[2];
    const float* ln_g = (const float*)d_in[7];
    const float* ln_b = (const float*)d_in[8];
    const float* Wh   = (const float*)d_in[9];
    const float* bh   = (const float*)d_in[10];
    const float* Wo   = (const float*)d_in[11];
    const float* bo   = (const float*)d_in[12];
    float* out = (float*)d_out;

    char* ws = (char*)d_ws;
    unsigned short* WhbT = (unsigned short*)ws;                    // 16,777,216 B
    float2* stats = (float2*)(ws + 16777216ull);                   //  4,194,304 B
    float* Cp     = (float*)(ws + 20971520ull);                    // 33,554,432 B
    float* WinT   = (float*)(ws + 54525952ull);                    //    131,072 B
    float* binT   = (float*)(ws + 54657024ull);                    //    131,072 B
    float* bias2  = (float*)(ws + 54788096ull);                    //      1,024 B

    hipLaunchKernelGGL(stats_k, dim3(1089), dim3(256), 0, stream,
                       arr, Win, bin, stats, WinT, binT, bias2);
    hipLaunchKernelGGL(prep_b, dim3(512, 4), dim3(256), 0, stream,
                       Wh, ln_g, ln_b, WhbT, bias2);
    hipLaunchKernelGGL(gemm_f, dim3(512), dim3(512), 0, stream,
                       arr, WinT, binT, stats, WhbT, Cp);
    hipLaunchKernelGGL(finale, dim3(NB), dim3(256), 0, stream,
                       Cp, bh, Wo, bo, bias2, out);
}